// Round 17
// baseline (621.961 us; speedup 1.0000x reference)
//
#include <hip/hip_runtime.h>
#include <hip/hip_bf16.h>
#include <cstdint>

#define B_  2
#define CK_ 64
#define NM_ 32768
#define NQ_ 4096
#define CV_ 256
#define K_  20
#define FDEPTH_ 11

typedef unsigned short ushort_t;
typedef unsigned int uint_t;
typedef unsigned long long u64_t;
typedef float f32x4 __attribute__((ext_vector_type(4)));
typedef float f32x16 __attribute__((ext_vector_type(16)));
typedef short short8v __attribute__((ext_vector_type(8)));

__device__ __forceinline__ ushort_t f2bf_rn(float f) {
  uint_t x = __float_as_uint(f);
  uint_t r = x + 0x7FFFu + ((x >> 16) & 1u);
  return (ushort_t)(r >> 16);
}
__device__ __forceinline__ float bf2f(ushort_t u) {
  return __uint_as_float(((uint_t)u) << 16);
}

// ------------------------------------------------------------------
// prep_mk: mk[b][c][m] fp32 -> chunk-tiled bf16 hi/lo:
//   layout: [b][gch(1024)][c8(8)][m&31(32)][8 bf16]
// ans = -0.125*||mk||^2 (ready as MFMA C-init)
__global__ __launch_bounds__(256) void prep_mk(const float* __restrict__ mk,
                                               ushort_t* __restrict__ mkt,
                                               ushort_t* __restrict__ mlt,
                                               float* __restrict__ ans) {
  int i = blockIdx.x * 256 + threadIdx.x;
  int b = i >> 15, m = i & (NM_ - 1);
  const float* src = mk + (size_t)b * CK_ * NM_ + m;
  const size_t chbase = ((size_t)(b * 1024 + (m >> 5)) << 11);
  const int ml = m & 31;
  float s = 0.f;
  #pragma unroll
  for (int c8 = 0; c8 < 8; ++c8) {
    ushort_t hh[8], ll[8];
    #pragma unroll
    for (int j = 0; j < 8; ++j) {
      float v = src[(size_t)(c8 * 8 + j) * NM_];
      s = fmaf(v, v, s);
      ushort_t h = f2bf_rn(v);
      hh[j] = h;
      ll[j] = f2bf_rn(v - bf2f(h));
    }
    size_t off = chbase + (c8 << 8) + (ml << 3);
    *reinterpret_cast<short8v*>(mkt + off) = *reinterpret_cast<short8v*>(hh);
    *reinterpret_cast<short8v*>(mlt + off) = *reinterpret_cast<short8v*>(ll);
  }
  ans[i] = -0.125f * s;
}

// prep_qk: qk[b][c][q] fp32 -> qkh/qkl[b][q][c] bf16 split of 0.25*qk
__global__ __launch_bounds__(256) void prep_qk(const float* __restrict__ qk,
                                               ushort_t* __restrict__ qkh,
                                               ushort_t* __restrict__ qkl) {
  int i = blockIdx.x * 256 + threadIdx.x;
  int b = i >> 12, q = i & (NQ_ - 1);
  const float* src = qk + (size_t)b * CK_ * NQ_ + q;
  ushort_t* dh = qkh + (size_t)i * CK_;
  ushort_t* dl = qkl + (size_t)i * CK_;
  #pragma unroll
  for (int c8 = 0; c8 < 8; ++c8) {
    ushort_t hh[8], ll[8];
    #pragma unroll
    for (int j = 0; j < 8; ++j) {
      float v = 0.25f * src[(size_t)(c8 * 8 + j) * NQ_];
      ushort_t h = f2bf_rn(v);
      hh[j] = h;
      ll[j] = f2bf_rn(v - bf2f(h));
    }
    *reinterpret_cast<short8v*>(dh + c8 * 8) = *reinterpret_cast<short8v*>(hh);
    *reinterpret_cast<short8v*>(dl + c8 * 8) = *reinterpret_cast<short8v*>(ll);
  }
}

// ------------------------------------------------------------------
// transpose_mv: float4 reads (16B/lane), bf16x8 writes (16B/lane, 128B contig)
__global__ __launch_bounds__(256) void transpose_mv(const float* __restrict__ mv0,
                                                    const float* __restrict__ mv1,
                                                    ushort_t* __restrict__ mvt0,
                                                    ushort_t* __restrict__ mvt1) {
  __shared__ float tl[64][33];
  const int zz = blockIdx.z;
  const int bank = zz & 1, b = zz >> 1;
  const float* src = (bank ? mv1 : mv0) + (size_t)b * CV_ * NM_;
  ushort_t*    dst = (bank ? mvt1 : mvt0) + (size_t)b * NM_ * CV_;
  const int m0 = blockIdx.x * 32, c0 = blockIdx.y * 64;
  const int t = threadIdx.x;
  #pragma unroll
  for (int i = 0; i < 2; ++i) {
    int f = t + 256 * i;
    int c = f >> 3, m4 = f & 7;
    f32x4 v = *reinterpret_cast<const f32x4*>(src + (size_t)(c0 + c) * NM_ + m0 + 4 * m4);
    tl[c][4 * m4 + 0] = v[0];
    tl[c][4 * m4 + 1] = v[1];
    tl[c][4 * m4 + 2] = v[2];
    tl[c][4 * m4 + 3] = v[3];
  }
  __syncthreads();
  int m = t >> 3, c8 = t & 7;
  ushort_t pack[8];
  #pragma unroll
  for (int j = 0; j < 8; ++j) pack[j] = f2bf_rn(tl[c8 * 8 + j][m]);
  *reinterpret_cast<short8v*>(dst + (size_t)(m0 + m) * CV_ + c0 + c8 * 8) =
      *reinterpret_cast<short8v*>(pack);
}

// ------------------------------------------------------------------
// exact fp32 top-20: named scalar pairs, fmax/fmin + cndmask ripple
#define TKF_FOR(F) F(0) F(1) F(2) F(3) F(4) F(5) F(6) F(7) F(8) F(9) F(10) F(11) F(12) F(13) F(14) F(15) F(16) F(17) F(18) F(19)
#define TKF_DECL(J) float tv##J = -3.4e38f; int ti##J = 0;

#define TKF_SW(A,B) { bool c_ = tv##B > tv##A; \
  float fx_ = fmaxf(tv##A, tv##B); float fn_ = fminf(tv##A, tv##B); \
  int ix_ = c_ ? ti##B : ti##A;    int in_ = c_ ? ti##A : ti##B; \
  tv##A = fx_; tv##B = fn_; ti##A = ix_; ti##B = in_; }

#define TKF_INS(S,M) { if ((S) > tv19) { tv19 = (S); ti19 = (M); \
  TKF_SW(18,19) TKF_SW(17,18) TKF_SW(16,17) TKF_SW(15,16) TKF_SW(14,15) \
  TKF_SW(13,14) TKF_SW(12,13) TKF_SW(11,12) TKF_SW(10,11) TKF_SW(9,10) \
  TKF_SW(8,9) TKF_SW(7,8) TKF_SW(6,7) TKF_SW(5,6) TKF_SW(4,5) \
  TKF_SW(3,4) TKF_SW(2,3) TKF_SW(1,2) TKF_SW(0,1) } }

// value-only ripple (pass 1: top-20 of chunk-maxes; no index)
#define TKV_SW(A,B) { float fx_ = fmaxf(tv##A, tv##B); float fn_ = fminf(tv##A, tv##B); \
  tv##A = fx_; tv##B = fn_; }
#define TKV_INS(S) { if ((S) > tv19) { tv19 = (S); \
  TKV_SW(18,19) TKV_SW(17,18) TKV_SW(16,17) TKV_SW(15,16) TKV_SW(14,15) \
  TKV_SW(13,14) TKV_SW(12,13) TKV_SW(11,12) TKV_SW(10,11) TKV_SW(9,10) \
  TKV_SW(8,9) TKV_SW(7,8) TKV_SW(6,7) TKV_SW(5,6) TKV_SW(4,5) \
  TKV_SW(3,4) TKV_SW(2,3) TKV_SW(1,2) TKV_SW(0,1) } }

// pass-2 FIFO push with >= threshold (tau may equal the 20th-best score)
#define TKF_PUSH2(S,M) { float s_ = (S); if (s_ >= thr) { \
  fifoW[cnt << 6] = (((u64_t)(uint_t)__float_as_uint(s_)) << 32) | (uint_t)(M); ++cnt; } }

// lane-parallel batched drain; thr = max(tau, own tv19, pair tv19)
#define TKF_DRAIN2() { \
  _Pragma("clang loop unroll(disable)") \
  for (int d_ = 0; d_ < FDEPTH_; ++d_) { \
    if (__all(cnt <= d_)) break; \
    u64_t pk_ = fifoW[d_ << 6]; \
    float s_ = __uint_as_float((uint_t)(pk_ >> 32)); \
    int m_ = (int)(uint_t)pk_; \
    if (d_ < cnt) { TKF_INS(s_, m_) } \
  } \
  cnt = 0; thr = fmaxf(tau, tv19); \
  thr = fmaxf(thr, __shfl_xor(thr, 32)); }

#define TKF_CHK2() { if (__any(cnt >= 8)) { TKF_DRAIN2() } }

#define MFMA32(A,B,C) __builtin_amdgcn_mfma_f32_32x32x16_bf16((A),(B),(C),0,0,0)

#define GLOAD_LDS16(G, L) __builtin_amdgcn_global_load_lds( \
    (__attribute__((address_space(1))) unsigned int*)(G), \
    (__attribute__((address_space(3))) unsigned int*)(L), 16, 0, 0)

// score + exact top-20, two-pass chunk-max threshold.
// block = 256 thr (4 waves) = 128 queries (2 thr/query). grid: (NQ/128, segcnt, B).
__global__ __launch_bounds__(256, 3) void score_topk_mfma(
    const ushort_t* __restrict__ mkt, const ushort_t* __restrict__ mlt,
    const ushort_t* __restrict__ qkh, const ushort_t* __restrict__ qkl,
    const float* __restrict__ ans,
    float* __restrict__ pvals, int* __restrict__ pidx) {
  __shared__ __attribute__((aligned(16))) ushort_t ldsH[2 * 2048];
  __shared__ __attribute__((aligned(16))) ushort_t ldsL[2 * 2048];
  __shared__ __attribute__((aligned(16))) float    ldsA[2 * 32];
  __shared__ __attribute__((aligned(16))) u64_t    fifo[4][FDEPTH_][64];
  const int t = threadIdx.x;
  const int b = blockIdx.z, seg = blockIdx.y, qblk = blockIdx.x;
  const int segcnt = gridDim.y;
  const int chunks = (NM_ / 32) / segcnt;    // 128 at segcnt=8 (even)
  const int w = t >> 6, l = t & 63;
  const int lq = l & 31, hi = l >> 5;
  const int q = qblk * 128 + w * 32 + lq;
  const int gch0 = seg * chunks;

  u64_t* fifoW = &fifo[w][0][l];

  // persistent B fragments (qk hi + lo)
  const size_t qbase = (((size_t)b * NQ_ + q) << 6) + hi * 8;
  const short8v bh0 = *(const short8v*)(qkh + qbase);
  const short8v bh1 = *(const short8v*)(qkh + qbase + 16);
  const short8v bh2 = *(const short8v*)(qkh + qbase + 32);
  const short8v bh3 = *(const short8v*)(qkh + qbase + 48);
  const short8v bl0 = *(const short8v*)(qkl + qbase);
  const short8v bl1 = *(const short8v*)(qkl + qbase + 16);
  const short8v bl2 = *(const short8v*)(qkl + qbase + 32);
  const short8v bl3 = *(const short8v*)(qkl + qbase + 48);

  TKF_FOR(TKF_DECL)
  float thr = -3.4e38f;
  float tau = -3.4e38f;
  int cnt = 0;

#define STAGE(NBUF, GCH) { \
  const size_t cb_ = ((size_t)(b * 1024) + (GCH)) << 11; \
  GLOAD_LDS16(mkt + cb_ + (((w << 6) + l) << 3), &ldsH[(NBUF) * 2048 + (w << 9)]); \
  GLOAD_LDS16(mlt + cb_ + (((w << 6) + l) << 3), &ldsL[(NBUF) * 2048 + (w << 9)]); \
  if (t < 8) GLOAD_LDS16(ans + ((size_t)b << 15) + ((GCH) << 5) + (t << 2), &ldsA[(NBUF) * 32]); \
}

// pipelined iteration: stage next, issue MFMAs into 3 independent 4-deep chains
// (hh->c1 init -||m||^2, hl->c2 init 0, lh->c3 init 0; round-robin issue),
// run SCANSTMT (over the PREVIOUS chunk's acc) while MFMAs drain, combine, barrier.
#define ITER_P(CH, BUF, ACC, SCANSTMT) { \
  { int chn_ = (CH) + 1; if (chn_ > chunks - 1) chn_ = chunks - 1; \
    STAGE(1 - (BUF), gch0 + chn_) } \
  const int fro_ = (BUF) * 2048 + (hi << 8) + (lq << 3); \
  const short8v ah0 = *(const short8v*)&ldsH[fro_ + 0 * 512]; \
  const short8v ah1 = *(const short8v*)&ldsH[fro_ + 1 * 512]; \
  const short8v ah2 = *(const short8v*)&ldsH[fro_ + 2 * 512]; \
  const short8v ah3 = *(const short8v*)&ldsH[fro_ + 3 * 512]; \
  const short8v al0 = *(const short8v*)&ldsL[fro_ + 0 * 512]; \
  const short8v al1 = *(const short8v*)&ldsL[fro_ + 1 * 512]; \
  const short8v al2 = *(const short8v*)&ldsL[fro_ + 2 * 512]; \
  const short8v al3 = *(const short8v*)&ldsL[fro_ + 3 * 512]; \
  const float* ap_ = &ldsA[(BUF) * 32 + (hi << 2)]; \
  f32x4 an_a = *(const f32x4*)ap_; \
  f32x4 an_b = *(const f32x4*)(ap_ + 8); \
  f32x4 an_c = *(const f32x4*)(ap_ + 16); \
  f32x4 an_d = *(const f32x4*)(ap_ + 24); \
  f32x16 c1_, c2_, c3_; \
  c1_[0]  = an_a[0]; c1_[1]  = an_a[1]; c1_[2]  = an_a[2]; c1_[3]  = an_a[3]; \
  c1_[4]  = an_b[0]; c1_[5]  = an_b[1]; c1_[6]  = an_b[2]; c1_[7]  = an_b[3]; \
  c1_[8]  = an_c[0]; c1_[9]  = an_c[1]; c1_[10] = an_c[2]; c1_[11] = an_c[3]; \
  c1_[12] = an_d[0]; c1_[13] = an_d[1]; c1_[14] = an_d[2]; c1_[15] = an_d[3]; \
  c2_ = 0.f; c3_ = 0.f; \
  c1_ = MFMA32(ah0, bh0, c1_);  c2_ = MFMA32(ah0, bl0, c2_);  c3_ = MFMA32(al0, bh0, c3_); \
  c1_ = MFMA32(ah1, bh1, c1_);  c2_ = MFMA32(ah1, bl1, c2_);  c3_ = MFMA32(al1, bh1, c3_); \
  c1_ = MFMA32(ah2, bh2, c1_);  c2_ = MFMA32(ah2, bl2, c2_);  c3_ = MFMA32(al2, bh2, c3_); \
  c1_ = MFMA32(ah3, bh3, c1_);  c2_ = MFMA32(ah3, bl3, c2_);  c3_ = MFMA32(al3, bh3, c3_); \
  SCANSTMT \
  ACC = c1_ + c2_ + c3_; \
  __syncthreads(); \
}

// pass-1 scan: chunk max (pair-combined) -> value-only top-20 ripple
#define MAXSCAN(ACC) { \
  float m0_ = fmaxf(fmaxf(ACC[0], ACC[1]),  fmaxf(ACC[2], ACC[3])); \
  float m1_ = fmaxf(fmaxf(ACC[4], ACC[5]),  fmaxf(ACC[6], ACC[7])); \
  float m2_ = fmaxf(fmaxf(ACC[8], ACC[9]),  fmaxf(ACC[10], ACC[11])); \
  float m3_ = fmaxf(fmaxf(ACC[12], ACC[13]), fmaxf(ACC[14], ACC[15])); \
  float cm_ = fmaxf(fmaxf(m0_, m1_), fmaxf(m2_, m3_)); \
  cm_ = fmaxf(cm_, __shfl_xor(cm_, 32)); \
  TKV_INS(cm_) \
}

// pass-2 scan: push scores >= thr into FIFO; check every 8 pushes
#define SCANP2(ACC, CHP) { \
  const int mbp_ = ((gch0 + (CHP)) << 5) + (hi << 2); \
  TKF_PUSH2(ACC[0], mbp_ + 0)  TKF_PUSH2(ACC[1], mbp_ + 1)  TKF_PUSH2(ACC[2], mbp_ + 2)  TKF_PUSH2(ACC[3], mbp_ + 3)  \
  TKF_CHK2() \
  TKF_PUSH2(ACC[4], mbp_ + 8)  TKF_PUSH2(ACC[5], mbp_ + 9)  TKF_PUSH2(ACC[6], mbp_ + 10) TKF_PUSH2(ACC[7], mbp_ + 11) \
  TKF_CHK2() \
  TKF_PUSH2(ACC[8], mbp_ + 16) TKF_PUSH2(ACC[9], mbp_ + 17) TKF_PUSH2(ACC[10], mbp_ + 18) TKF_PUSH2(ACC[11], mbp_ + 19) \
  TKF_CHK2() \
  TKF_PUSH2(ACC[12], mbp_ + 24) TKF_PUSH2(ACC[13], mbp_ + 25) TKF_PUSH2(ACC[14], mbp_ + 26) TKF_PUSH2(ACC[15], mbp_ + 27) \
  TKF_CHK2() }

  f32x16 accA, accB;

  // ================= PASS 1: chunk maxes -> tau =================
  STAGE(0, gch0)
  __syncthreads();

  ITER_P(0, 0, accA, {})
  ITER_P(1, 1, accB, MAXSCAN(accA))
  #pragma clang loop unroll(disable)
  for (int ch2 = 1; ch2 <= chunks / 2 - 1; ++ch2) {
    const int ch = ch2 * 2;
    ITER_P(ch,     0, accA, MAXSCAN(accB))
    ITER_P(ch + 1, 1, accB, MAXSCAN(accA))
  }
  MAXSCAN(accB)

  tau = tv19;   // 20th-largest chunk-max = lower bound on query's 20th-best score

  // reset top-20 state for pass 2
#define TKF_RST(J) { tv##J = -3.4e38f; ti##J = 0; }
  TKF_FOR(TKF_RST)
#undef TKF_RST
  thr = tau;
  cnt = 0;

  // ================= PASS 2: exact top-20 over candidates >= tau =================
  STAGE(0, gch0)
  __syncthreads();

  ITER_P(0, 0, accA, {})
  ITER_P(1, 1, accB, SCANP2(accA, 0))
  #pragma clang loop unroll(disable)
  for (int ch2 = 1; ch2 <= chunks / 2 - 1; ++ch2) {
    const int ch = ch2 * 2;
    ITER_P(ch,     0, accA, SCANP2(accB, ch - 1))
    ITER_P(ch + 1, 1, accB, SCANP2(accA, ch))
  }
  SCANP2(accB, chunks - 1)
  if (__any(cnt > 0)) { TKF_DRAIN2() }

#undef ITER_P
#undef SCANP2
#undef MAXSCAN
#undef STAGE

  const int part = (seg << 1) + hi;
  const int parts = segcnt << 1;
  float* pv = pvals + (((size_t)((b * parts + part) * K_)) << 12) + q;
  int*   pi = pidx  + (((size_t)((b * parts + part) * K_)) << 12) + q;
#define TKF_STORE(J) { pv[(size_t)(J) << 12] = tv##J; pi[(size_t)(J) << 12] = ti##J; }
  TKF_FOR(TKF_STORE)
#undef TKF_STORE
}

// ------------------------------------------------------------------
// merge partitions + softmax. Partitions are sorted desc -> early-exit.
__global__ __launch_bounds__(256) void merge_kernel(const float* __restrict__ pvals,
                                                    const int* __restrict__ pidx,
                                                    float* __restrict__ fw,
                                                    int* __restrict__ fidx, int S) {
  int i = blockIdx.x * 256 + threadIdx.x;
  int b = i >> 12, q = i & (NQ_ - 1);

  float vals[K_]; int idxs[K_];
  #pragma unroll
  for (int j = 0; j < K_; ++j) { vals[j] = -3.4e38f; idxs[j] = 0; }

  for (int seg = 0; seg < S; ++seg) {
    const float* pp = pvals + (((size_t)((b * S + seg) * K_)) << 12) + q;
    const int*   qq = pidx  + (((size_t)((b * S + seg) * K_)) << 12) + q;
    #pragma clang loop unroll(disable)
    for (int j = 0; j < K_; ++j) {
      float v = pp[(size_t)j << 12];
      if (__all(v <= vals[K_ - 1])) break;
      if (v > vals[K_ - 1]) {
        int m = qq[(size_t)j << 12];
        vals[K_ - 1] = v; idxs[K_ - 1] = m;
        #pragma unroll
        for (int jj = K_ - 1; jj > 0; --jj) {
          if (vals[jj] > vals[jj - 1]) {
            float tv = vals[jj]; vals[jj] = vals[jj - 1]; vals[jj - 1] = tv;
            int   ti = idxs[jj]; idxs[jj] = idxs[jj - 1]; idxs[jj - 1] = ti;
          }
        }
      }
    }
  }

  float mx = vals[0];
  float w[K_]; float sum = 0.f;
  #pragma unroll
  for (int j = 0; j < K_; ++j) { w[j] = expf(vals[j] - mx); sum += w[j]; }
  float inv = 1.f / sum;
  #pragma unroll
  for (int j = 0; j < K_; ++j) {
    size_t o = (size_t)(b * K_ + j) * NQ_ + q;
    fw[o] = w[j] * inv; fidx[o] = idxs[j];
  }
}

// ------------------------------------------------------------------
__global__ __launch_bounds__(256) void readout_bf16(const ushort_t* __restrict__ mvt0,
                                                    const ushort_t* __restrict__ mvt1,
                                                    const float* __restrict__ fw,
                                                    const int* __restrict__ fidx,
                                                    float* __restrict__ out) {
  __shared__ float mw[16][K_];
  __shared__ int   mi[16][K_];
  __shared__ float ob0[256][17];
  __shared__ float ob1[256][17];
  const int t = threadIdx.x;
  const int b = blockIdx.y;
  const int q0 = blockIdx.x * 16;

  for (int i = t; i < 16 * K_; i += 256) {
    int qp = i / K_, k = i % K_;
    size_t o = (size_t)(b * K_ + k) * NQ_ + q0 + qp;
    mw[qp][k] = fw[o];
    mi[qp][k] = fidx[o];
  }
  __syncthreads();

  const int c2 = (t & 127) * 2, hq = t >> 7;
  for (int qp = hq * 8; qp < hq * 8 + 8; ++qp) {
    float a00 = 0.f, a01 = 0.f, a10 = 0.f, a11 = 0.f;
    #pragma unroll 5
    for (int k = 0; k < K_; ++k) {
      int m = mi[qp][k]; float ww = mw[qp][k];
      size_t o = ((size_t)(b * NM_ + m) << 8) + c2;
      uint_t v0 = *reinterpret_cast<const uint_t*>(mvt0 + o);
      uint_t v1 = *reinterpret_cast<const uint_t*>(mvt1 + o);
      a00 = fmaf(ww, __uint_as_float(v0 << 16), a00);
      a01 = fmaf(ww, __uint_as_float(v0 & 0xFFFF0000u), a01);
      a10 = fmaf(ww, __uint_as_float(v1 << 16), a10);
      a11 = fmaf(ww, __uint_as_float(v1 & 0xFFFF0000u), a11);
    }
    ob0[c2][qp] = a00; ob0[c2 + 1][qp] = a01;
    ob1[c2][qp] = a10; ob1[c2 + 1][qp] = a11;
  }
  __syncthreads();

  float* out0 = out + (size_t)b * CV_ * NQ_;
  float* out1 = out + (size_t)B_ * CV_ * NQ_ + (size_t)b * CV_ * NQ_;
  for (int i = t; i < 256 * 16; i += 256) {
    int c = i >> 4, qp = i & 15;
    out0[(size_t)c * NQ_ + q0 + qp] = ob0[c][qp];
    out1[(size_t)c * NQ_ + q0 + qp] = ob1[c][qp];
  }
}

__global__ __launch_bounds__(256) void readout_f32(const float* __restrict__ v0src,
                                                   const float* __restrict__ v1src,
                                                   const float* __restrict__ fw,
                                                   const int* __restrict__ fidx,
                                                   float* __restrict__ out) {
  __shared__ float mw[16][K_];
  __shared__ int   mi[16][K_];
  __shared__ float ob0[256][17];
  __shared__ float ob1[256][17];
  const int t = threadIdx.x;
  const int b = blockIdx.y;
  const int q0 = blockIdx.x * 16;

  for (int i = t; i < 16 * K_; i += 256) {
    int qp = i / K_, k = i % K_;
    size_t o = (size_t)(b * K_ + k) * NQ_ + q0 + qp;
    mw[qp][k] = fw[o];
    mi[qp][k] = fidx[o];
  }
  __syncthreads();

  for (int qp = 0; qp < 16; ++qp) {
    float a0 = 0.f, a1 = 0.f;
    #pragma unroll 5
    for (int k = 0; k < K_; ++k) {
      int m = mi[qp][k]; float ww = mw[qp][k];
      size_t o = (size_t)b * CV_ * NM_ + (size_t)t * NM_ + m;
      a0 = fmaf(ww, v0src[o], a0);
      a1 = fmaf(ww, v1src[o], a1);
    }
    ob0[t][qp] = a0; ob1[t][qp] = a1;
  }
  __syncthreads();

  float* out0 = out + (size_t)b * CV_ * NQ_;
  float* out1 = out + (size_t)B_ * CV_ * NQ_ + (size_t)b * CV_ * NQ_;
  for (int i = t; i < 256 * 16; i += 256) {
    int c = i >> 4, qp = i & 15;
    out0[(size_t)c * NQ_ + q0 + qp] = ob0[c][qp];
    out1[(size_t)c * NQ_ + q0 + qp] = ob1[c][qp];
  }
}

// ------------------------------------------------------------------
extern "C" void kernel_launch(void* const* d_in, const int* in_sizes, int n_in,
                              void* d_out, int out_size, void* d_ws, size_t ws_size,
                              hipStream_t stream) {
  (void)in_sizes; (void)n_in; (void)out_size;
  const float* mk  = (const float*)d_in[0];
  const float* qk  = (const float*)d_in[1];
  const float* mv0 = (const float*)d_in[2];
  const float* mv1 = (const float*)d_in[3];
  float* out = (float*)d_out;

  auto al = [](size_t x) { return (x + 255) & ~(size_t)255; };
  const size_t mkB  = (size_t)B_ * NM_ * CK_ * 2;
  const size_t qkB  = (size_t)B_ * NQ_ * CK_ * 2;
  const size_t anB  = (size_t)B_ * NM_ * 4;
  const size_t finB = (size_t)B_ * K_ * NQ_ * 4;
  const size_t tpB  = (size_t)B_ * NM_ * CV_ * 2;
  auto prtB = [](int parts) { return (size_t)B_ * parts * K_ * NQ_ * 4; };
  auto core = [&](int parts) {
    return 2 * al(mkB) + 2 * al(qkB) + al(anB) + 2 * al(prtB(parts)) + 2 * al(finB);
  };

  int segcnt; bool tp;
  if      (ws_size >= core(16) + 2 * al(tpB)) { segcnt = 8; tp = true;  }
  else if (ws_size >= core(16))               { segcnt = 8; tp = false; }
  else                                        { segcnt = 4; tp = false; }
  const int parts = segcnt * 2;

  char* p = (char*)d_ws;
  ushort_t* mkt = (ushort_t*)p; p += al(mkB);
  ushort_t* mlt = (ushort_t*)p; p += al(mkB);
  ushort_t* qkh = (ushort_t*)p; p += al(qkB);
  ushort_t* qkl = (ushort_t*)p; p += al(qkB);
  float* ans    = (float*)p;    p += al(anB);
  float* pvals  = (float*)p;    p += al(prtB(parts));
  int*   pidx   = (int*)p;      p += al(prtB(parts));
  float* fw     = (float*)p;    p += al(finB);
  int*   fidx   = (int*)p;      p += al(finB);
  ushort_t* mvt0 = nullptr, * mvt1 = nullptr;
  if (tp) { mvt0 = (ushort_t*)p; p += al(tpB); mvt1 = (ushort_t*)p; p += al(tpB); }

  prep_mk<<<B_ * NM_ / 256, 256, 0, stream>>>(mk, mkt, mlt, ans);
  prep_qk<<<B_ * NQ_ / 256, 256, 0, stream>>>(qk, qkh, qkl);
  if (tp)
    transpose_mv<<<dim3(NM_ / 32, CV_ / 64, B_ * 2), 256, 0, stream>>>(mv0, mv1, mvt0, mvt1);
  score_topk_mfma<<<dim3(NQ_ / 128, segcnt, B_), 256, 0, stream>>>(mkt, mlt, qkh, qkl, ans, pvals, pidx);
  merge_kernel<<<B_ * NQ_ / 256, 256, 0, stream>>>(pvals, pidx, fw, fidx, parts);
  if (tp) readout_bf16<<<dim3(NQ_ / 16, B_), 256, 0, stream>>>(mvt0, mvt1, fw, fidx, out);
  else    readout_f32<<<dim3(NQ_ / 16, B_), 256, 0, stream>>>(mv0, mv1, fw, fidx, out);
}

// Round 18
// 489.006 us; speedup vs baseline: 1.2719x; 1.2719x over previous
//
#include <hip/hip_runtime.h>
#include <hip/hip_bf16.h>
#include <cstdint>

#define B_  2
#define CK_ 64
#define NM_ 32768
#define NQ_ 4096
#define CV_ 256
#define K_  20
#define FDEPTH_ 11

typedef unsigned short ushort_t;
typedef unsigned int uint_t;
typedef unsigned long long u64_t;
typedef float f32x4 __attribute__((ext_vector_type(4)));
typedef float f32x16 __attribute__((ext_vector_type(16)));
typedef short short8v __attribute__((ext_vector_type(8)));

__device__ __forceinline__ ushort_t f2bf_rn(float f) {
  uint_t x = __float_as_uint(f);
  uint_t r = x + 0x7FFFu + ((x >> 16) & 1u);
  return (ushort_t)(r >> 16);
}
__device__ __forceinline__ float bf2f(ushort_t u) {
  return __uint_as_float(((uint_t)u) << 16);
}

// ------------------------------------------------------------------
// prep_mk: mk[b][c][m] fp32 -> chunk-tiled bf16 hi/lo:
//   layout: [b][gch(1024)][c8(8)][m&31(32)][8 bf16]
// ans = -0.125*||mk||^2 (ready as MFMA C-init)
__global__ __launch_bounds__(256) void prep_mk(const float* __restrict__ mk,
                                               ushort_t* __restrict__ mkt,
                                               ushort_t* __restrict__ mlt,
                                               float* __restrict__ ans) {
  int i = blockIdx.x * 256 + threadIdx.x;
  int b = i >> 15, m = i & (NM_ - 1);
  const float* src = mk + (size_t)b * CK_ * NM_ + m;
  const size_t chbase = ((size_t)(b * 1024 + (m >> 5)) << 11);
  const int ml = m & 31;
  float s = 0.f;
  #pragma unroll
  for (int c8 = 0; c8 < 8; ++c8) {
    ushort_t hh[8], ll[8];
    #pragma unroll
    for (int j = 0; j < 8; ++j) {
      float v = src[(size_t)(c8 * 8 + j) * NM_];
      s = fmaf(v, v, s);
      ushort_t h = f2bf_rn(v);
      hh[j] = h;
      ll[j] = f2bf_rn(v - bf2f(h));
    }
    size_t off = chbase + (c8 << 8) + (ml << 3);
    *reinterpret_cast<short8v*>(mkt + off) = *reinterpret_cast<short8v*>(hh);
    *reinterpret_cast<short8v*>(mlt + off) = *reinterpret_cast<short8v*>(ll);
  }
  ans[i] = -0.125f * s;
}

// prep_qk: qk[b][c][q] fp32 -> qkh/qkl[b][q][c] bf16 split of 0.25*qk
__global__ __launch_bounds__(256) void prep_qk(const float* __restrict__ qk,
                                               ushort_t* __restrict__ qkh,
                                               ushort_t* __restrict__ qkl) {
  int i = blockIdx.x * 256 + threadIdx.x;
  int b = i >> 12, q = i & (NQ_ - 1);
  const float* src = qk + (size_t)b * CK_ * NQ_ + q;
  ushort_t* dh = qkh + (size_t)i * CK_;
  ushort_t* dl = qkl + (size_t)i * CK_;
  #pragma unroll
  for (int c8 = 0; c8 < 8; ++c8) {
    ushort_t hh[8], ll[8];
    #pragma unroll
    for (int j = 0; j < 8; ++j) {
      float v = 0.25f * src[(size_t)(c8 * 8 + j) * NQ_];
      ushort_t h = f2bf_rn(v);
      hh[j] = h;
      ll[j] = f2bf_rn(v - bf2f(h));
    }
    *reinterpret_cast<short8v*>(dh + c8 * 8) = *reinterpret_cast<short8v*>(hh);
    *reinterpret_cast<short8v*>(dl + c8 * 8) = *reinterpret_cast<short8v*>(ll);
  }
}

// ------------------------------------------------------------------
// transpose_mv: float4 reads (16B/lane), bf16x8 writes (16B/lane, 128B contig)
__global__ __launch_bounds__(256) void transpose_mv(const float* __restrict__ mv0,
                                                    const float* __restrict__ mv1,
                                                    ushort_t* __restrict__ mvt0,
                                                    ushort_t* __restrict__ mvt1) {
  __shared__ float tl[64][33];
  const int zz = blockIdx.z;
  const int bank = zz & 1, b = zz >> 1;
  const float* src = (bank ? mv1 : mv0) + (size_t)b * CV_ * NM_;
  ushort_t*    dst = (bank ? mvt1 : mvt0) + (size_t)b * NM_ * CV_;
  const int m0 = blockIdx.x * 32, c0 = blockIdx.y * 64;
  const int t = threadIdx.x;
  #pragma unroll
  for (int i = 0; i < 2; ++i) {
    int f = t + 256 * i;
    int c = f >> 3, m4 = f & 7;
    f32x4 v = *reinterpret_cast<const f32x4*>(src + (size_t)(c0 + c) * NM_ + m0 + 4 * m4);
    tl[c][4 * m4 + 0] = v[0];
    tl[c][4 * m4 + 1] = v[1];
    tl[c][4 * m4 + 2] = v[2];
    tl[c][4 * m4 + 3] = v[3];
  }
  __syncthreads();
  int m = t >> 3, c8 = t & 7;
  ushort_t pack[8];
  #pragma unroll
  for (int j = 0; j < 8; ++j) pack[j] = f2bf_rn(tl[c8 * 8 + j][m]);
  *reinterpret_cast<short8v*>(dst + (size_t)(m0 + m) * CV_ + c0 + c8 * 8) =
      *reinterpret_cast<short8v*>(pack);
}

// ------------------------------------------------------------------
// exact fp32 top-20: named scalar pairs, fmax/fmin + cndmask ripple
#define TKF_FOR(F) F(0) F(1) F(2) F(3) F(4) F(5) F(6) F(7) F(8) F(9) F(10) F(11) F(12) F(13) F(14) F(15) F(16) F(17) F(18) F(19)
#define TKF_DECL(J) float tv##J = -3.4e38f; int ti##J = 0;

#define TKF_SW(A,B) { bool c_ = tv##B > tv##A; \
  float fx_ = fmaxf(tv##A, tv##B); float fn_ = fminf(tv##A, tv##B); \
  int ix_ = c_ ? ti##B : ti##A;    int in_ = c_ ? ti##A : ti##B; \
  tv##A = fx_; tv##B = fn_; ti##A = ix_; ti##B = in_; }

#define TKF_INS(S,M) { if ((S) > tv19) { tv19 = (S); ti19 = (M); \
  TKF_SW(18,19) TKF_SW(17,18) TKF_SW(16,17) TKF_SW(15,16) TKF_SW(14,15) \
  TKF_SW(13,14) TKF_SW(12,13) TKF_SW(11,12) TKF_SW(10,11) TKF_SW(9,10) \
  TKF_SW(8,9) TKF_SW(7,8) TKF_SW(6,7) TKF_SW(5,6) TKF_SW(4,5) \
  TKF_SW(3,4) TKF_SW(2,3) TKF_SW(1,2) TKF_SW(0,1) } }

// value-only ripple (pass 1: top-20 of chunk-maxes; no index)
#define TKV_SW(A,B) { float fx_ = fmaxf(tv##A, tv##B); float fn_ = fminf(tv##A, tv##B); \
  tv##A = fx_; tv##B = fn_; }
#define TKV_INS(S) { if ((S) > tv19) { tv19 = (S); \
  TKV_SW(18,19) TKV_SW(17,18) TKV_SW(16,17) TKV_SW(15,16) TKV_SW(14,15) \
  TKV_SW(13,14) TKV_SW(12,13) TKV_SW(11,12) TKV_SW(10,11) TKV_SW(9,10) \
  TKV_SW(8,9) TKV_SW(7,8) TKV_SW(6,7) TKV_SW(5,6) TKV_SW(4,5) \
  TKV_SW(3,4) TKV_SW(2,3) TKV_SW(1,2) TKV_SW(0,1) } }

// pass-2 FIFO push with >= threshold (tau may equal the 20th-best score)
#define TKF_PUSH2(S,M) { float s_ = (S); if (s_ >= thr) { \
  fifoW[cnt << 6] = (((u64_t)(uint_t)__float_as_uint(s_)) << 32) | (uint_t)(M); ++cnt; } }

// lane-parallel batched drain; thr = max(tau, own tv19, pair tv19)
#define TKF_DRAIN2() { \
  _Pragma("clang loop unroll(disable)") \
  for (int d_ = 0; d_ < FDEPTH_; ++d_) { \
    if (__all(cnt <= d_)) break; \
    u64_t pk_ = fifoW[d_ << 6]; \
    float s_ = __uint_as_float((uint_t)(pk_ >> 32)); \
    int m_ = (int)(uint_t)pk_; \
    if (d_ < cnt) { TKF_INS(s_, m_) } \
  } \
  cnt = 0; thr = fmaxf(tau, tv19); \
  thr = fmaxf(thr, __shfl_xor(thr, 32)); }

#define TKF_CHK2() { if (__any(cnt >= 8)) { TKF_DRAIN2() } }

#define MFMA32(A,B,C) __builtin_amdgcn_mfma_f32_32x32x16_bf16((A),(B),(C),0,0,0)

#define GLOAD_LDS16(G, L) __builtin_amdgcn_global_load_lds( \
    (__attribute__((address_space(1))) unsigned int*)(G), \
    (__attribute__((address_space(3))) unsigned int*)(L), 16, 0, 0)

// score + exact top-20, two-pass chunk-max threshold.
// block = 256 thr (4 waves) = 128 queries (2 thr/query). grid: (NQ/128, segcnt, B).
__global__ __launch_bounds__(256, 3) void score_topk_mfma(
    const ushort_t* __restrict__ mkt, const ushort_t* __restrict__ mlt,
    const ushort_t* __restrict__ qkh, const ushort_t* __restrict__ qkl,
    const float* __restrict__ ans,
    float* __restrict__ pvals, int* __restrict__ pidx) {
  __shared__ __attribute__((aligned(16))) ushort_t ldsH[2 * 2048];
  __shared__ __attribute__((aligned(16))) ushort_t ldsL[2 * 2048];
  __shared__ __attribute__((aligned(16))) float    ldsA[2 * 32];
  __shared__ __attribute__((aligned(16))) u64_t    fifo[4][FDEPTH_][64];
  const int t = threadIdx.x;
  const int b = blockIdx.z, seg = blockIdx.y, qblk = blockIdx.x;
  const int segcnt = gridDim.y;
  const int chunks = (NM_ / 32) / segcnt;    // 128 at segcnt=8 (even)
  const int w = t >> 6, l = t & 63;
  const int lq = l & 31, hi = l >> 5;
  const int q = qblk * 128 + w * 32 + lq;
  const int gch0 = seg * chunks;

  u64_t* fifoW = &fifo[w][0][l];

  // persistent B fragments (qk hi + lo)
  const size_t qbase = (((size_t)b * NQ_ + q) << 6) + hi * 8;
  const short8v bh0 = *(const short8v*)(qkh + qbase);
  const short8v bh1 = *(const short8v*)(qkh + qbase + 16);
  const short8v bh2 = *(const short8v*)(qkh + qbase + 32);
  const short8v bh3 = *(const short8v*)(qkh + qbase + 48);
  const short8v bl0 = *(const short8v*)(qkl + qbase);
  const short8v bl1 = *(const short8v*)(qkl + qbase + 16);
  const short8v bl2 = *(const short8v*)(qkl + qbase + 32);
  const short8v bl3 = *(const short8v*)(qkl + qbase + 48);

  TKF_FOR(TKF_DECL)
  float thr = -3.4e38f;
  float tau = -3.4e38f;
  int cnt = 0;

#define STAGE(NBUF, GCH) { \
  const size_t cb_ = ((size_t)(b * 1024) + (GCH)) << 11; \
  GLOAD_LDS16(mkt + cb_ + (((w << 6) + l) << 3), &ldsH[(NBUF) * 2048 + (w << 9)]); \
  GLOAD_LDS16(mlt + cb_ + (((w << 6) + l) << 3), &ldsL[(NBUF) * 2048 + (w << 9)]); \
  if (t < 8) GLOAD_LDS16(ans + ((size_t)b << 15) + ((GCH) << 5) + (t << 2), &ldsA[(NBUF) * 32]); \
}

// pipelined iteration: stage next, issue MFMAs into 2 independent chains,
// run SCANSTMT (over the PREVIOUS chunk's acc) while MFMAs drain, combine, barrier.
#define ITER_P(CH, BUF, ACC, SCANSTMT) { \
  { int chn_ = (CH) + 1; if (chn_ > chunks - 1) chn_ = chunks - 1; \
    STAGE(1 - (BUF), gch0 + chn_) } \
  const int fro_ = (BUF) * 2048 + (hi << 8) + (lq << 3); \
  const short8v ah0 = *(const short8v*)&ldsH[fro_ + 0 * 512]; \
  const short8v ah1 = *(const short8v*)&ldsH[fro_ + 1 * 512]; \
  const short8v ah2 = *(const short8v*)&ldsH[fro_ + 2 * 512]; \
  const short8v ah3 = *(const short8v*)&ldsH[fro_ + 3 * 512]; \
  const short8v al0 = *(const short8v*)&ldsL[fro_ + 0 * 512]; \
  const short8v al1 = *(const short8v*)&ldsL[fro_ + 1 * 512]; \
  const short8v al2 = *(const short8v*)&ldsL[fro_ + 2 * 512]; \
  const short8v al3 = *(const short8v*)&ldsL[fro_ + 3 * 512]; \
  const float* ap_ = &ldsA[(BUF) * 32 + (hi << 2)]; \
  f32x4 an_a = *(const f32x4*)ap_; \
  f32x4 an_b = *(const f32x4*)(ap_ + 8); \
  f32x4 an_c = *(const f32x4*)(ap_ + 16); \
  f32x4 an_d = *(const f32x4*)(ap_ + 24); \
  f32x16 c1_, c2_; \
  c1_[0]  = an_a[0]; c1_[1]  = an_a[1]; c1_[2]  = an_a[2]; c1_[3]  = an_a[3]; \
  c1_[4]  = an_b[0]; c1_[5]  = an_b[1]; c1_[6]  = an_b[2]; c1_[7]  = an_b[3]; \
  c1_[8]  = an_c[0]; c1_[9]  = an_c[1]; c1_[10] = an_c[2]; c1_[11] = an_c[3]; \
  c1_[12] = an_d[0]; c1_[13] = an_d[1]; c1_[14] = an_d[2]; c1_[15] = an_d[3]; \
  c2_ = 0.f; \
  c1_ = MFMA32(ah0, bh0, c1_);  c2_ = MFMA32(ah0, bl0, c2_); \
  c1_ = MFMA32(ah1, bh1, c1_);  c2_ = MFMA32(al0, bh0, c2_); \
  c1_ = MFMA32(ah2, bh2, c1_);  c2_ = MFMA32(ah1, bl1, c2_); \
  c1_ = MFMA32(ah3, bh3, c1_);  c2_ = MFMA32(al1, bh1, c2_); \
  c2_ = MFMA32(ah2, bl2, c2_); \
  c2_ = MFMA32(al2, bh2, c2_); \
  c2_ = MFMA32(ah3, bl3, c2_); \
  c2_ = MFMA32(al3, bh3, c2_); \
  SCANSTMT \
  ACC = c1_ + c2_; \
  __syncthreads(); \
}

// pass-1 scan: chunk max (pair-combined) -> value-only top-20 ripple
#define MAXSCAN(ACC) { \
  float m0_ = fmaxf(fmaxf(ACC[0], ACC[1]),  fmaxf(ACC[2], ACC[3])); \
  float m1_ = fmaxf(fmaxf(ACC[4], ACC[5]),  fmaxf(ACC[6], ACC[7])); \
  float m2_ = fmaxf(fmaxf(ACC[8], ACC[9]),  fmaxf(ACC[10], ACC[11])); \
  float m3_ = fmaxf(fmaxf(ACC[12], ACC[13]), fmaxf(ACC[14], ACC[15])); \
  float cm_ = fmaxf(fmaxf(m0_, m1_), fmaxf(m2_, m3_)); \
  cm_ = fmaxf(cm_, __shfl_xor(cm_, 32)); \
  TKV_INS(cm_) \
}

// pass-2 scan: push scores >= thr into FIFO; check every 4 pushes
#define SCANP2(ACC, CHP) { \
  const int mbp_ = ((gch0 + (CHP)) << 5) + (hi << 2); \
  TKF_PUSH2(ACC[0], mbp_ + 0)  TKF_PUSH2(ACC[1], mbp_ + 1)  TKF_PUSH2(ACC[2], mbp_ + 2)  TKF_PUSH2(ACC[3], mbp_ + 3)  \
  TKF_CHK2() \
  TKF_PUSH2(ACC[4], mbp_ + 8)  TKF_PUSH2(ACC[5], mbp_ + 9)  TKF_PUSH2(ACC[6], mbp_ + 10) TKF_PUSH2(ACC[7], mbp_ + 11) \
  TKF_CHK2() \
  TKF_PUSH2(ACC[8], mbp_ + 16) TKF_PUSH2(ACC[9], mbp_ + 17) TKF_PUSH2(ACC[10], mbp_ + 18) TKF_PUSH2(ACC[11], mbp_ + 19) \
  TKF_CHK2() \
  TKF_PUSH2(ACC[12], mbp_ + 24) TKF_PUSH2(ACC[13], mbp_ + 25) TKF_PUSH2(ACC[14], mbp_ + 26) TKF_PUSH2(ACC[15], mbp_ + 27) \
  TKF_CHK2() }

  f32x16 accA, accB;

  // ================= PASS 1: chunk maxes -> tau =================
  STAGE(0, gch0)
  __syncthreads();

  ITER_P(0, 0, accA, {})
  ITER_P(1, 1, accB, MAXSCAN(accA))
  #pragma clang loop unroll(disable)
  for (int ch2 = 1; ch2 <= chunks / 2 - 1; ++ch2) {
    const int ch = ch2 * 2;
    ITER_P(ch,     0, accA, MAXSCAN(accB))
    ITER_P(ch + 1, 1, accB, MAXSCAN(accA))
  }
  MAXSCAN(accB)

  tau = tv19;   // 20th-largest chunk-max = lower bound on query's 20th-best score

  // reset top-20 state for pass 2
#define TKF_RST(J) { tv##J = -3.4e38f; ti##J = 0; }
  TKF_FOR(TKF_RST)
#undef TKF_RST
  thr = tau;
  cnt = 0;

  // ================= PASS 2: exact top-20 over candidates >= tau =================
  STAGE(0, gch0)
  __syncthreads();

  ITER_P(0, 0, accA, {})
  ITER_P(1, 1, accB, SCANP2(accA, 0))
  #pragma clang loop unroll(disable)
  for (int ch2 = 1; ch2 <= chunks / 2 - 1; ++ch2) {
    const int ch = ch2 * 2;
    ITER_P(ch,     0, accA, SCANP2(accB, ch - 1))
    ITER_P(ch + 1, 1, accB, SCANP2(accA, ch))
  }
  SCANP2(accB, chunks - 1)
  if (__any(cnt > 0)) { TKF_DRAIN2() }

#undef ITER_P
#undef SCANP2
#undef MAXSCAN
#undef STAGE

  const int part = (seg << 1) + hi;
  const int parts = segcnt << 1;
  float* pv = pvals + (((size_t)((b * parts + part) * K_)) << 12) + q;
  int*   pi = pidx  + (((size_t)((b * parts + part) * K_)) << 12) + q;
#define TKF_STORE(J) { pv[(size_t)(J) << 12] = tv##J; pi[(size_t)(J) << 12] = ti##J; }
  TKF_FOR(TKF_STORE)
#undef TKF_STORE
}

// ------------------------------------------------------------------
// merge partitions + softmax. Partitions are sorted desc -> early-exit.
__global__ __launch_bounds__(256) void merge_kernel(const float* __restrict__ pvals,
                                                    const int* __restrict__ pidx,
                                                    float* __restrict__ fw,
                                                    int* __restrict__ fidx, int S) {
  int i = blockIdx.x * 256 + threadIdx.x;
  int b = i >> 12, q = i & (NQ_ - 1);

  float vals[K_]; int idxs[K_];
  #pragma unroll
  for (int j = 0; j < K_; ++j) { vals[j] = -3.4e38f; idxs[j] = 0; }

  for (int seg = 0; seg < S; ++seg) {
    const float* pp = pvals + (((size_t)((b * S + seg) * K_)) << 12) + q;
    const int*   qq = pidx  + (((size_t)((b * S + seg) * K_)) << 12) + q;
    #pragma clang loop unroll(disable)
    for (int j = 0; j < K_; ++j) {
      float v = pp[(size_t)j << 12];
      if (__all(v <= vals[K_ - 1])) break;
      if (v > vals[K_ - 1]) {
        int m = qq[(size_t)j << 12];
        vals[K_ - 1] = v; idxs[K_ - 1] = m;
        #pragma unroll
        for (int jj = K_ - 1; jj > 0; --jj) {
          if (vals[jj] > vals[jj - 1]) {
            float tv = vals[jj]; vals[jj] = vals[jj - 1]; vals[jj - 1] = tv;
            int   ti = idxs[jj]; idxs[jj] = idxs[jj - 1]; idxs[jj - 1] = ti;
          }
        }
      }
    }
  }

  float mx = vals[0];
  float w[K_]; float sum = 0.f;
  #pragma unroll
  for (int j = 0; j < K_; ++j) { w[j] = expf(vals[j] - mx); sum += w[j]; }
  float inv = 1.f / sum;
  #pragma unroll
  for (int j = 0; j < K_; ++j) {
    size_t o = (size_t)(b * K_ + j) * NQ_ + q;
    fw[o] = w[j] * inv; fidx[o] = idxs[j];
  }
}

// ------------------------------------------------------------------
__global__ __launch_bounds__(256) void readout_bf16(const ushort_t* __restrict__ mvt0,
                                                    const ushort_t* __restrict__ mvt1,
                                                    const float* __restrict__ fw,
                                                    const int* __restrict__ fidx,
                                                    float* __restrict__ out) {
  __shared__ float mw[16][K_];
  __shared__ int   mi[16][K_];
  __shared__ float ob0[256][17];
  __shared__ float ob1[256][17];
  const int t = threadIdx.x;
  const int b = blockIdx.y;
  const int q0 = blockIdx.x * 16;

  for (int i = t; i < 16 * K_; i += 256) {
    int qp = i / K_, k = i % K_;
    size_t o = (size_t)(b * K_ + k) * NQ_ + q0 + qp;
    mw[qp][k] = fw[o];
    mi[qp][k] = fidx[o];
  }
  __syncthreads();

  const int c2 = (t & 127) * 2, hq = t >> 7;
  for (int qp = hq * 8; qp < hq * 8 + 8; ++qp) {
    float a00 = 0.f, a01 = 0.f, a10 = 0.f, a11 = 0.f;
    #pragma unroll 5
    for (int k = 0; k < K_; ++k) {
      int m = mi[qp][k]; float ww = mw[qp][k];
      size_t o = ((size_t)(b * NM_ + m) << 8) + c2;
      uint_t v0 = *reinterpret_cast<const uint_t*>(mvt0 + o);
      uint_t v1 = *reinterpret_cast<const uint_t*>(mvt1 + o);
      a00 = fmaf(ww, __uint_as_float(v0 << 16), a00);
      a01 = fmaf(ww, __uint_as_float(v0 & 0xFFFF0000u), a01);
      a10 = fmaf(ww, __uint_as_float(v1 << 16), a10);
      a11 = fmaf(ww, __uint_as_float(v1 & 0xFFFF0000u), a11);
    }
    ob0[c2][qp] = a00; ob0[c2 + 1][qp] = a01;
    ob1[c2][qp] = a10; ob1[c2 + 1][qp] = a11;
  }
  __syncthreads();

  float* out0 = out + (size_t)b * CV_ * NQ_;
  float* out1 = out + (size_t)B_ * CV_ * NQ_ + (size_t)b * CV_ * NQ_;
  for (int i = t; i < 256 * 16; i += 256) {
    int c = i >> 4, qp = i & 15;
    out0[(size_t)c * NQ_ + q0 + qp] = ob0[c][qp];
    out1[(size_t)c * NQ_ + q0 + qp] = ob1[c][qp];
  }
}

__global__ __launch_bounds__(256) void readout_f32(const float* __restrict__ v0src,
                                                   const float* __restrict__ v1src,
                                                   const float* __restrict__ fw,
                                                   const int* __restrict__ fidx,
                                                   float* __restrict__ out) {
  __shared__ float mw[16][K_];
  __shared__ int   mi[16][K_];
  __shared__ float ob0[256][17];
  __shared__ float ob1[256][17];
  const int t = threadIdx.x;
  const int b = blockIdx.y;
  const int q0 = blockIdx.x * 16;

  for (int i = t; i < 16 * K_; i += 256) {
    int qp = i / K_, k = i % K_;
    size_t o = (size_t)(b * K_ + k) * NQ_ + q0 + qp;
    mw[qp][k] = fw[o];
    mi[qp][k] = fidx[o];
  }
  __syncthreads();

  for (int qp = 0; qp < 16; ++qp) {
    float a0 = 0.f, a1 = 0.f;
    #pragma unroll 5
    for (int k = 0; k < K_; ++k) {
      int m = mi[qp][k]; float ww = mw[qp][k];
      size_t o = (size_t)b * CV_ * NM_ + (size_t)t * NM_ + m;
      a0 = fmaf(ww, v0src[o], a0);
      a1 = fmaf(ww, v1src[o], a1);
    }
    ob0[t][qp] = a0; ob1[t][qp] = a1;
  }
  __syncthreads();

  float* out0 = out + (size_t)b * CV_ * NQ_;
  float* out1 = out + (size_t)B_ * CV_ * NQ_ + (size_t)b * CV_ * NQ_;
  for (int i = t; i < 256 * 16; i += 256) {
    int c = i >> 4, qp = i & 15;
    out0[(size_t)c * NQ_ + q0 + qp] = ob0[c][qp];
    out1[(size_t)c * NQ_ + q0 + qp] = ob1[c][qp];
  }
}

// ------------------------------------------------------------------
extern "C" void kernel_launch(void* const* d_in, const int* in_sizes, int n_in,
                              void* d_out, int out_size, void* d_ws, size_t ws_size,
                              hipStream_t stream) {
  (void)in_sizes; (void)n_in; (void)out_size;
  const float* mk  = (const float*)d_in[0];
  const float* qk  = (const float*)d_in[1];
  const float* mv0 = (const float*)d_in[2];
  const float* mv1 = (const float*)d_in[3];
  float* out = (float*)d_out;

  auto al = [](size_t x) { return (x + 255) & ~(size_t)255; };
  const size_t mkB  = (size_t)B_ * NM_ * CK_ * 2;
  const size_t qkB  = (size_t)B_ * NQ_ * CK_ * 2;
  const size_t anB  = (size_t)B_ * NM_ * 4;
  const size_t finB = (size_t)B_ * K_ * NQ_ * 4;
  const size_t tpB  = (size_t)B_ * NM_ * CV_ * 2;
  auto prtB = [](int parts) { return (size_t)B_ * parts * K_ * NQ_ * 4; };
  auto core = [&](int parts) {
    return 2 * al(mkB) + 2 * al(qkB) + al(anB) + 2 * al(prtB(parts)) + 2 * al(finB);
  };

  int segcnt; bool tp;
  if      (ws_size >= core(16) + 2 * al(tpB)) { segcnt = 8; tp = true;  }
  else if (ws_size >= core(16))               { segcnt = 8; tp = false; }
  else                                        { segcnt = 4; tp = false; }
  const int parts = segcnt * 2;

  char* p = (char*)d_ws;
  ushort_t* mkt = (ushort_t*)p; p += al(mkB);
  ushort_t* mlt = (ushort_t*)p; p += al(mkB);
  ushort_t* qkh = (ushort_t*)p; p += al(qkB);
  ushort_t* qkl = (ushort_t*)p; p += al(qkB);
  float* ans    = (float*)p;    p += al(anB);
  float* pvals  = (float*)p;    p += al(prtB(parts));
  int*   pidx   = (int*)p;      p += al(prtB(parts));
  float* fw     = (float*)p;    p += al(finB);
  int*   fidx   = (int*)p;      p += al(finB);
  ushort_t* mvt0 = nullptr, * mvt1 = nullptr;
  if (tp) { mvt0 = (ushort_t*)p; p += al(tpB); mvt1 = (ushort_t*)p; p += al(tpB); }

  prep_mk<<<B_ * NM_ / 256, 256, 0, stream>>>(mk, mkt, mlt, ans);
  prep_qk<<<B_ * NQ_ / 256, 256, 0, stream>>>(qk, qkh, qkl);
  if (tp)
    transpose_mv<<<dim3(NM_ / 32, CV_ / 64, B_ * 2), 256, 0, stream>>>(mv0, mv1, mvt0, mvt1);
  score_topk_mfma<<<dim3(NQ_ / 128, segcnt, B_), 256, 0, stream>>>(mkt, mlt, qkh, qkl, ans, pvals, pidx);
  merge_kernel<<<B_ * NQ_ / 256, 256, 0, stream>>>(pvals, pidx, fw, fidx, parts);
  if (tp) readout_bf16<<<dim3(NQ_ / 16, B_), 256, 0, stream>>>(mvt0, mvt1, fw, fidx, out);
  else    readout_f32<<<dim3(NQ_ / 16, B_), 256, 0, stream>>>(mv0, mv1, fw, fidx, out);
}